// Round 5
// baseline (204.819 us; speedup 1.0000x reference)
//
#include <hip/hip_runtime.h>
#include <stdint.h>

// ODE sampler (VP-SDE probability-flow, RK4, T=50) for B=2048, D=16, H=256.
// tr(J) analytic: tr = -0.5*beta*(D + sum_k (1-h_k^2)*c_k).
//
// R5 vs R4 (155us kernel, VALUBusy 63%, structurally capped at 2 waves/SIMD
// with one wave per sample): split each sample across TWO waves.
//  - block = 128 thr (2 waves), one sample per block, 2048 blocks
//    -> 8 blocks/CU, 16 waves/CU, 4 waves/SIMD (2x R4's TLP); barrier stalls
//    of one block covered by 7 independent blocks on the CU (R2's failure was
//    4-wave blocks at 4 blocks/CU with fp32 dots).
//  - wave W: phase-1 owns k in [128W,128W+128) (2 k's/lane: 16 fdot2 + 2 tanh,
//    halving the quarter-rate transcendental cost per wave);
//    phase-2 owns outputs i in [8W,8W+8) over all 256 k (16 fdot2 + 3 shfl).
//  - 2 two-wave barriers per Feval; h chunk-padded (20 dwords per 32-k chunk:
//    read bank-quads (5c+m)%8 all distinct -> conflict-free).
//  - f16 packed weights/activations, fp32 accumulate; deferred ldj (per-lane
//    partials, one butterfly + tiny LDS combine at kernel end). Same numerics
//    as R4 (absmax 0.5 vs 1.68 threshold).

typedef _Float16 f16x2 __attribute__((ext_vector_type(2)));

#if defined(__has_builtin)
#if __has_builtin(__builtin_amdgcn_fdot2)
#define HAVE_FDOT2 1
#endif
#endif

__device__ __forceinline__ float fdot2f(f16x2 a, f16x2 b, float c) {
#ifdef HAVE_FDOT2
    return __builtin_amdgcn_fdot2(a, b, c, false);
#else
    return fmaf((float)a.y, (float)b.y, fmaf((float)a.x, (float)b.x, c));
#endif
}

__device__ __forceinline__ uint32_t pk(float a, float b) {
    f16x2 v; v.x = (_Float16)a; v.y = (_Float16)b;   // RNE casts
    return __builtin_bit_cast(uint32_t, v);
}
__device__ __forceinline__ f16x2 upk(uint32_t u) {
    return __builtin_bit_cast(f16x2, u);
}

#define Bn 2048
#define Dn 16
#define Hn 256
#define Tn 50
#define BLK 128
#define CH 20          // dwords per 32-k h chunk: 16 data + 4 pad

__global__ __launch_bounds__(BLK, 4) void ode_kernel(
    const float* __restrict__ x_in,   // [B][D]
    const float* __restrict__ W1,     // [D][H]
    const float* __restrict__ b1v,    // [H]
    const float* __restrict__ wtv,    // [H]
    const float* __restrict__ W2,     // [H][D]
    const float* __restrict__ b2v,    // [D]
    float* __restrict__ out)          // xf[B*D] | ldjf[B] | xt[T*B*D]
{
    __shared__ __align__(16) uint32_t h_lds[8 * CH];  // h, f16-pair packed
    __shared__ __align__(16) _Float16 xe[16];         // eval point, f16
    __shared__ float ldj_part[2];

    const int t    = threadIdx.x;
    const int W    = t >> 6;          // wave 0/1
    const int L    = t & 63;
    const int iloc = L >> 3;
    const int c    = L & 7;           // phase-2 k-chunk (32 k's)
    const int i    = 8 * W + iloc;    // phase-2 output dim
    const int kp   = 64 * W + L;      // phase-1 h-pair: k = 2kp, 2kp+1
    const int gs   = blockIdx.x;      // one sample per block

    // ---- one-time init: weights packed to f16 registers ----
    f16x2 w1p[2][8];                  // [q][j] = {W1[2j][2kp+q], W1[2j+1][2kp+q]}
    float b1k[2], wtk[2], ck[2];
    #pragma unroll
    for (int q = 0; q < 2; ++q) {
        const int k = 2 * kp + q;
        #pragma unroll
        for (int j = 0; j < 8; ++j) {
            f16x2 v;
            v.x = (_Float16)W1[(2 * j)     * Hn + k];
            v.y = (_Float16)W1[(2 * j + 1) * Hn + k];
            w1p[q][j] = v;
        }
        b1k[q] = b1v[k];
        wtk[q] = wtv[k];
        float s = 0.f;
        #pragma unroll
        for (int ii = 0; ii < 16; ++ii)
            s = fmaf(W1[ii * Hn + k], W2[k * Dn + ii], s);
        ck[q] = s;
    }
    f16x2 w2s[16];                    // [m] = {W2[32c+2m][i], W2[32c+2m+1][i]}
    #pragma unroll
    for (int m = 0; m < 16; ++m) {
        f16x2 v;
        v.x = (_Float16)W2[(32 * c + 2 * m)     * Dn + i];
        v.y = (_Float16)W2[(32 * c + 2 * m + 1) * Dn + i];
        w2s[m] = v;
    }
    const float b2i = b2v[i];

    float x    = x_in[gs * Dn + i];   // state x_i (replicated over 8 c-lanes)
    float ldjl = 0.f;                 // per-lane ldj partial (deferred)

    float* xf_out  = out;
    float* ldj_out = out + (size_t)Bn * Dn;
    float* xt_base = out + (size_t)Bn * Dn + Bn + gs * Dn + i;

    if (c == 0) xt_base[0] = x;       // xt[0]

    const int hwidx = CH * (kp >> 4) + (kp & 15);   // padded h write index

    // Feval: assumes xe[] valid (caller wrote + barrier). Returns dx_i.
    auto Feval = [&](float xev, float tt, float wgt) -> float {
        // ---- phase 1: this lane's 2 hidden units ----
        const uint4 xl0 = *(const uint4*)&xe[0];
        const uint4 xl1 = *(const uint4*)&xe[8];
        const f16x2 xp[8] = { upk(xl0.x), upk(xl0.y), upk(xl0.z), upk(xl0.w),
                              upk(xl1.x), upk(xl1.y), upk(xl1.z), upk(xl1.w) };
        float u0 = fmaf(tt, wtk[0], b1k[0]);
        float u1 = fmaf(tt, wtk[1], b1k[1]);
        #pragma unroll
        for (int j = 0; j < 8; ++j) {
            u0 = fdot2f(xp[j], w1p[0][j], u0);
            u1 = fdot2f(xp[j], w1p[1][j], u1);
        }
        // tanh(u) = 1 - 2/(e^{2u}+1); exp over/underflow saturates correctly
        const float h0 = fmaf(-2.f, __builtin_amdgcn_rcpf(__expf(2.f * u0) + 1.f), 1.f);
        const float h1 = fmaf(-2.f, __builtin_amdgcn_rcpf(__expf(2.f * u1) + 1.f), 1.f);
        h_lds[hwidx] = pk(h0, h1);

        const float gl = fmaf(-h0 * h0, ck[0], ck[0]) + fmaf(-h1 * h1, ck[1], ck[1]);
        const float beta = fmaf(tt, 19.9f, 0.1f);
        const float nhb  = -0.5f * beta;
        ldjl = fmaf(wgt * nhb, 0.125f + gl, ldjl);   // 16/128 per lane

        __syncthreads();              // h complete (both waves)

        // ---- phase 2: score for dim i over k-chunk c (all 256 k via 2 waves) ----
        float s0 = 0.f, s1 = 0.f;
        #pragma unroll
        for (int mq = 0; mq < 4; ++mq) {
            const uint4 hv = *(const uint4*)&h_lds[CH * c + 4 * mq];
            s0 = fdot2f(upk(hv.x), w2s[4 * mq + 0], s0);
            s1 = fdot2f(upk(hv.y), w2s[4 * mq + 1], s1);
            s0 = fdot2f(upk(hv.z), w2s[4 * mq + 2], s0);
            s1 = fdot2f(upk(hv.w), w2s[4 * mq + 3], s1);
        }
        float sc = s0 + s1;
        sc += __shfl_xor(sc, 1);
        sc += __shfl_xor(sc, 2);
        sc += __shfl_xor(sc, 4);      // all 8 c-lanes hold full sc_i
        sc += b2i;
        return nhb * (xev + sc);
    };

    auto put_xe = [&](float v) {      // write eval point; caller barriers
        if (c == 0) xe[i] = (_Float16)v;
    };

    const float t_lo = 1e-3f;
    const float dt   = (1.0f - 1e-3f) / (float)(Tn - 1);

    put_xe(x);
    __syncthreads();

    for (int j = 0; j < Tn - 1; ++j) {
        const float t0  = fmaf((float)j,       dt, t_lo);
        const float t1  = fmaf((float)(j + 1), dt, t_lo);
        const float hh  = t1 - t0;
        const float tm  = t0 + 0.5f * hh;
        const float w1w = hh * (1.f / 6.f);
        const float w2w = hh * (2.f / 6.f);

        const float k1 = Feval(x, t0, w1w);
        const float e2 = fmaf(0.5f * hh, k1, x);
        put_xe(e2); __syncthreads();
        const float k2 = Feval(e2, tm, w2w);
        const float e3 = fmaf(0.5f * hh, k2, x);
        put_xe(e3); __syncthreads();
        const float k3 = Feval(e3, tm, w2w);
        const float e4 = fmaf(hh, k3, x);
        put_xe(e4); __syncthreads();
        const float k4 = Feval(e4, t1, w1w);

        x = fmaf(w1w, k1 + 2.f * (k2 + k3) + k4, x);
        if (c == 0) xt_base[(size_t)(j + 1) * (Bn * Dn)] = x;
        put_xe(x); __syncthreads();
    }

    if (c == 0) xf_out[gs * Dn + i] = x;

    // ---- deferred ldj reduction: wave butterfly + 2-way LDS combine ----
    #pragma unroll
    for (int off = 1; off < 64; off <<= 1)
        ldjl += __shfl_xor(ldjl, off);
    if (L == 0) ldj_part[W] = ldjl;
    __syncthreads();
    if (t == 0) ldj_out[gs] = ldj_part[0] + ldj_part[1];
}

extern "C" void kernel_launch(void* const* d_in, const int* in_sizes, int n_in,
                              void* d_out, int out_size, void* d_ws, size_t ws_size,
                              hipStream_t stream) {
    const float* x  = (const float*)d_in[0];
    const float* W1 = (const float*)d_in[1];
    const float* b1 = (const float*)d_in[2];
    const float* wt = (const float*)d_in[3];
    const float* W2 = (const float*)d_in[4];
    const float* b2 = (const float*)d_in[5];
    (void)in_sizes; (void)n_in; (void)out_size; (void)d_ws; (void)ws_size;
    ode_kernel<<<Bn, BLK, 0, stream>>>(x, W1, b1, wt, W2, b2, (float*)d_out);
}

// Round 6
// 171.609 us; speedup vs baseline: 1.1935x; 1.1935x over previous
//
#include <hip/hip_runtime.h>
#include <stdint.h>

// ODE sampler (VP-SDE probability-flow, RK4, T=50) for B=2048, D=16, H=256.
// tr(J) analytic: tr = -0.5*beta*(D + sum_k (1-h_k^2)*c_k).
//
// R6: R4's barrier-free one-wave-per-sample base, with DS-pipe traffic (the
// measured ~78%-busy shared resource) moved to VALU/SALU:
//  - eval-point broadcast via v_readlane -> 8 SGPRs (f16 pairs); phase-1
//    fdot2 reads the SGPR directly. (-2 b128 DS reads/Feval + kills the
//    xe write->read dependency)
//  - score reduction via DPP adds (quad_perm 0xB1/0x4E + row_half_mirror),
//    VALU pipe, not ds_bpermute. (-6 DS ops/Feval)
//  - remaining DS/Feval: 1 b64 h write + 4 b128 h reads (conflict-free:
//    chunk stride 20 dwords -> read bank-quads (5c+m)%8 all distinct).
//  - W1/b1/wt prescaled by 2*log2(e): tanh = v_exp2+add+rcp+fma.
//  - ldj constant term folded out of the loop (wbsum); RK coeffs hoisted.

typedef _Float16 f16x2 __attribute__((ext_vector_type(2)));

#if defined(__has_builtin)
#if __has_builtin(__builtin_amdgcn_fdot2)
#define HAVE_FDOT2 1
#endif
#endif

__device__ __forceinline__ float fdot2f(f16x2 a, f16x2 b, float c) {
#ifdef HAVE_FDOT2
    return __builtin_amdgcn_fdot2(a, b, c, false);
#else
    return fmaf((float)a.y, (float)b.y, fmaf((float)a.x, (float)b.x, c));
#endif
}

__device__ __forceinline__ uint32_t pk(float a, float b) {
    f16x2 v; v.x = (_Float16)a; v.y = (_Float16)b;   // RNE casts
    return __builtin_bit_cast(uint32_t, v);
}
__device__ __forceinline__ f16x2 upk(uint32_t u) {
    return __builtin_bit_cast(f16x2, u);
}

// DPP add: x + x_from(lane permuted by ctrl); VALU pipe, no DS.
#define DPP_XOR1 0xB1    // quad_perm [1,0,3,2]
#define DPP_XOR2 0x4E    // quad_perm [2,3,0,1]
#define DPP_RHM  0x141   // row_half_mirror (xor-7 within 8-lane half-row)
template <int CTRL>
__device__ __forceinline__ float dpp_add(float x) {
    int v = __builtin_amdgcn_update_dpp(
        0, __builtin_bit_cast(int, x), CTRL, 0xF, 0xF, true);
    return x + __builtin_bit_cast(float, v);
}

#define Bn 2048
#define Dn 16
#define Hn 256
#define Tn 50
#define CH 20            // dwords per 32-k h chunk: 16 data + 4 pad

__global__ __launch_bounds__(64) void ode_kernel(
    const float* __restrict__ x_in,   // [B][D]
    const float* __restrict__ W1,     // [D][H]
    const float* __restrict__ b1v,    // [H]
    const float* __restrict__ wtv,    // [H]
    const float* __restrict__ W2,     // [H][D]
    const float* __restrict__ b2v,    // [D]
    float* __restrict__ out)          // xf[B*D] | ldjf[B] | xt[T*B*D]
{
    __shared__ __align__(16) uint32_t h_lds[8 * CH];  // h, f16-pair packed

    const int L  = threadIdx.x;       // one wave per block = one sample
    const int g8 = L >> 3;            // i-pair group 0..7
    const int c  = L & 7;             // phase-2 k-chunk (32 k's)
    const int ia = 2 * g8, ib = ia + 1;
    const int k0 = 4 * L;             // phase-1: this lane's 4 hidden units
    const int gs = blockIdx.x;

    const float K2 = 2.88539008f;     // 2*log2(e): u' = K2*u, exp2(u') = e^{2u}

    // ---- one-time init: weights packed to f16 registers ----
    f16x2 w1p[4][8];                  // prescaled: {K2*W1[2j][k0+q], K2*W1[2j+1][k0+q]}
    float b1k[4], wtk[4], ck[4];
    #pragma unroll
    for (int q = 0; q < 4; ++q) {
        const int k = k0 + q;
        #pragma unroll
        for (int j = 0; j < 8; ++j) {
            f16x2 v;
            v.x = (_Float16)(K2 * W1[(2 * j)     * Hn + k]);
            v.y = (_Float16)(K2 * W1[(2 * j + 1) * Hn + k]);
            w1p[q][j] = v;
        }
        b1k[q] = K2 * b1v[k];
        wtk[q] = K2 * wtv[k];
        float s = 0.f;                // ck from ORIGINAL f32 weights
        #pragma unroll
        for (int ii = 0; ii < 16; ++ii)
            s = fmaf(W1[ii * Hn + k], W2[k * Dn + ii], s);
        ck[q] = s;
    }
    f16x2 w2a[16], w2b[16];           // [m] = {W2[32c+2m][i*], W2[32c+2m+1][i*]}
    #pragma unroll
    for (int m = 0; m < 16; ++m) {
        f16x2 va, vb;
        va.x = (_Float16)W2[(32 * c + 2 * m)     * Dn + ia];
        va.y = (_Float16)W2[(32 * c + 2 * m + 1) * Dn + ia];
        vb.x = (_Float16)W2[(32 * c + 2 * m)     * Dn + ib];
        vb.y = (_Float16)W2[(32 * c + 2 * m + 1) * Dn + ib];
        w2a[m] = va; w2b[m] = vb;
    }
    const float b2a = b2v[ia], b2b = b2v[ib];

    float xa = x_in[gs * Dn + ia];
    float xb = x_in[gs * Dn + ib];
    float ldjl  = 0.f;                // per-lane ldj partial
    float wbsum = 0.f;                // sum of RK-weighted (-beta/2) factors

    float* xf_out  = out;
    float* ldj_out = out + (size_t)Bn * Dn;
    float* xt_ptr  = out + (size_t)Bn * Dn + Bn + gs * Dn + ia;

    if (c == 0) *(float2*)xt_ptr = make_float2(xa, xb);   // xt[0]
    xt_ptr += Bn * Dn;

    const int hwidx = CH * (L >> 3) + 2 * (L & 7);        // h write slot (b64)

    // eval-point broadcast registers (uniform -> SGPRs)
    uint32_t se0, se1, se2, se3, se4, se5, se6, se7;
    auto bcast = [&](float ea, float eb) {
        const uint32_t vpk = pk(ea, eb);      // every lane packs ITS pair
        se0 = __builtin_amdgcn_readlane(vpk,  0);
        se1 = __builtin_amdgcn_readlane(vpk,  8);
        se2 = __builtin_amdgcn_readlane(vpk, 16);
        se3 = __builtin_amdgcn_readlane(vpk, 24);
        se4 = __builtin_amdgcn_readlane(vpk, 32);
        se5 = __builtin_amdgcn_readlane(vpk, 40);
        se6 = __builtin_amdgcn_readlane(vpk, 48);
        se7 = __builtin_amdgcn_readlane(vpk, 56);
    };

    auto Feval = [&](float xeva, float xevb, float tt, float wgt,
                     float& dxa, float& dxb) {
        // ---- phase 1: this lane's 4 hidden units (SGPR-broadcast x) ----
        const f16x2 xp[8] = { upk(se0), upk(se1), upk(se2), upk(se3),
                              upk(se4), upk(se5), upk(se6), upk(se7) };
        float u0 = fmaf(tt, wtk[0], b1k[0]);
        float u1 = fmaf(tt, wtk[1], b1k[1]);
        float u2 = fmaf(tt, wtk[2], b1k[2]);
        float u3 = fmaf(tt, wtk[3], b1k[3]);
        #pragma unroll
        for (int j = 0; j < 8; ++j) {
            u0 = fdot2f(xp[j], w1p[0][j], u0);
            u1 = fdot2f(xp[j], w1p[1][j], u1);
            u2 = fdot2f(xp[j], w1p[2][j], u2);
            u3 = fdot2f(xp[j], w1p[3][j], u3);
        }
        // u is prescaled: exp2(u) = e^{2u_true}. tanh = 1 - 2/(E+1);
        // E->inf => h=1, E->0 => h=-1: saturation correct, no clamp.
        const float h0 = fmaf(-2.f, __builtin_amdgcn_rcpf(__builtin_amdgcn_exp2f(u0) + 1.f), 1.f);
        const float h1 = fmaf(-2.f, __builtin_amdgcn_rcpf(__builtin_amdgcn_exp2f(u1) + 1.f), 1.f);
        const float h2 = fmaf(-2.f, __builtin_amdgcn_rcpf(__builtin_amdgcn_exp2f(u2) + 1.f), 1.f);
        const float h3 = fmaf(-2.f, __builtin_amdgcn_rcpf(__builtin_amdgcn_exp2f(u3) + 1.f), 1.f);
        *(uint2*)&h_lds[hwidx] = make_uint2(pk(h0, h1), pk(h2, h3));

        // trace partial + deferred ldj (independent work inside the DS bubble)
        const float gl = (fmaf(-h0 * h0, ck[0], ck[0]) + fmaf(-h1 * h1, ck[1], ck[1]))
                       + (fmaf(-h2 * h2, ck[2], ck[2]) + fmaf(-h3 * h3, ck[3], ck[3]));
        const float beta = fmaf(tt, 19.9f, 0.1f);
        const float nhb  = -0.5f * beta;
        const float wb   = wgt * nhb;
        ldjl  = fmaf(wb, gl, ldjl);
        wbsum += wb;

        asm volatile("" ::: "memory");     // keep h write above the reads

        // ---- phase 2: score for (ia, ib) over k-chunk c ----
        float sa0 = 0.f, sa1 = 0.f, sb0 = 0.f, sb1 = 0.f;
        #pragma unroll
        for (int mq = 0; mq < 4; ++mq) {
            const uint4 hv = *(const uint4*)&h_lds[CH * c + 4 * mq];
            const f16x2 p0 = upk(hv.x), p1 = upk(hv.y), p2 = upk(hv.z), p3 = upk(hv.w);
            sa0 = fdot2f(p0, w2a[4 * mq + 0], sa0);
            sb0 = fdot2f(p0, w2b[4 * mq + 0], sb0);
            sa1 = fdot2f(p1, w2a[4 * mq + 1], sa1);
            sb1 = fdot2f(p1, w2b[4 * mq + 1], sb1);
            sa0 = fdot2f(p2, w2a[4 * mq + 2], sa0);
            sb0 = fdot2f(p2, w2b[4 * mq + 2], sb0);
            sa1 = fdot2f(p3, w2a[4 * mq + 3], sa1);
            sb1 = fdot2f(p3, w2b[4 * mq + 3], sb1);
        }
        float sca = sa0 + sa1, scb = sb0 + sb1;
        // 8-lane reduce on the VALU pipe (DPP), no DS ops:
        sca = dpp_add<DPP_XOR1>(sca);  scb = dpp_add<DPP_XOR1>(scb);
        sca = dpp_add<DPP_XOR2>(sca);  scb = dpp_add<DPP_XOR2>(scb);
        sca = dpp_add<DPP_RHM >(sca);  scb = dpp_add<DPP_RHM >(scb);
        sca += b2a;  scb += b2b;

        dxa = nhb * (xeva + sca);
        dxb = nhb * (xevb + scb);
    };

    const float t_lo = 1e-3f;
    const float dt   = (1.0f - 1e-3f) / (float)(Tn - 1);
    const float hh   = dt;                 // uniform step
    const float w1w  = hh * (1.f / 6.f);
    const float w2w  = hh * (2.f / 6.f);

    bcast(xa, xb);
    for (int j = 0; j < Tn - 1; ++j) {
        const float t0 = fmaf((float)j, dt, t_lo);
        const float tm = t0 + 0.5f * hh;
        const float t1 = t0 + hh;
        float k1a, k1b, k2a, k2b, k3a, k3b, k4a, k4b;

        Feval(xa, xb, t0, w1w, k1a, k1b);
        const float e2a = fmaf(0.5f * hh, k1a, xa);
        const float e2b = fmaf(0.5f * hh, k1b, xb);
        bcast(e2a, e2b);
        Feval(e2a, e2b, tm, w2w, k2a, k2b);
        const float e3a = fmaf(0.5f * hh, k2a, xa);
        const float e3b = fmaf(0.5f * hh, k2b, xb);
        bcast(e3a, e3b);
        Feval(e3a, e3b, tm, w2w, k3a, k3b);
        const float e4a = fmaf(hh, k3a, xa);
        const float e4b = fmaf(hh, k3b, xb);
        bcast(e4a, e4b);
        Feval(e4a, e4b, t1, w1w, k4a, k4b);

        xa = fmaf(w1w, k1a + 2.f * (k2a + k3a) + k4a, xa);
        xb = fmaf(w1w, k1b + 2.f * (k2b + k3b) + k4b, xb);
        if (c == 0) *(float2*)xt_ptr = make_float2(xa, xb);
        xt_ptr += Bn * Dn;
        bcast(xa, xb);
    }

    if (c == 0) *(float2*)(xf_out + gs * Dn + ia) = make_float2(xa, xb);

    // ldj: add folded constant term (16/64 per lane), then one-time butterfly
    ldjl = fmaf(0.25f, wbsum, ldjl);
    #pragma unroll
    for (int off = 1; off < 64; off <<= 1)
        ldjl += __shfl_xor(ldjl, off);
    if (L == 0) ldj_out[gs] = ldjl;
}

extern "C" void kernel_launch(void* const* d_in, const int* in_sizes, int n_in,
                              void* d_out, int out_size, void* d_ws, size_t ws_size,
                              hipStream_t stream) {
    const float* x  = (const float*)d_in[0];
    const float* W1 = (const float*)d_in[1];
    const float* b1 = (const float*)d_in[2];
    const float* wt = (const float*)d_in[3];
    const float* W2 = (const float*)d_in[4];
    const float* b2 = (const float*)d_in[5];
    (void)in_sizes; (void)n_in; (void)out_size; (void)d_ws; (void)ws_size;
    ode_kernel<<<Bn, 64, 0, stream>>>(x, W1, b1, wt, W2, b2, (float*)d_out);
}